// Round 2
// baseline (664.805 us; speedup 1.0000x reference)
//
#include <hip/hip_runtime.h>
#include <math.h>

#define NUM_EXPERTS 8
#define CAPACITY 320
#define NGROUP 8
#define NTOK 2048
#define HID 2048
#define NTOKENS (NGROUP * NTOK)  // 16384

// Kernel A: router logits + softmax max + argmax.
// Block = 512 threads = 32 teams of 16 lanes; one token per team.
// W (8x2048 f32 = 64 KB) is staged once per block into LDS, so the K-loop's
// VMEM queue holds ONLY hs loads -> 4 float4 loads in flight per wave is
// ample MLP. 512 blocks x 8 waves = 16 waves/CU (LDS 128 KB/CU caps at 2
// blocks/CU). fp64 accumulation, per-lane order and butterfly identical to
// the R1-verified kernel -> bit-identical logits.
__global__ __launch_bounds__(512, 4) void router_logits_kernel(
    const float* __restrict__ hs, const float* __restrict__ Wt,
    const float* __restrict__ bias,
    float* __restrict__ out_logits, float* __restrict__ out_pmax,
    int* __restrict__ ws_idx)
{
    __shared__ float4 ldsW[NUM_EXPERTS * (HID / 4)];  // [e][512] float4 = 64 KB

    const int tid = threadIdx.x;

    // Stage W: 512 threads x 8 float4 = 4096 float4 = 64 KB, coalesced.
    const float4* Wv = (const float4*)Wt;
#pragma unroll
    for (int k = 0; k < 8; ++k)
        ldsW[tid + k * 512] = Wv[tid + k * 512];
    __syncthreads();

    const int c    = tid & 15;   // lane within team
    const int team = tid >> 4;   // 0..31
    const int tok  = blockIdx.x * 32 + team;

    const float4* hsv = (const float4*)(hs + (size_t)tok * HID);

    double acc[NUM_EXPERTS];
#pragma unroll
    for (int e = 0; e < NUM_EXPERTS; ++e) acc[e] = 0.0;

    for (int i = 0; i < 32; i += 4) {
        // 4 hs chunks in flight before any use.
        float4 a0 = hsv[(i + 0) * 16 + c];
        float4 a1 = hsv[(i + 1) * 16 + c];
        float4 a2 = hsv[(i + 2) * 16 + c];
        float4 a3 = hsv[(i + 3) * 16 + c];

        const float4 av[4] = {a0, a1, a2, a3};
#pragma unroll
        for (int j = 0; j < 4; ++j) {
            const int q = (i + j) * 16 + c;
            double ax = (double)av[j].x, ay = (double)av[j].y;
            double az = (double)av[j].z, aw = (double)av[j].w;
#pragma unroll
            for (int e = 0; e < NUM_EXPERTS; ++e) {
                float4 w = ldsW[e * 512 + q];
                acc[e] += ax * (double)w.x + ay * (double)w.y +
                          az * (double)w.z + aw * (double)w.w;
            }
        }
    }

    // Butterfly over the 4 chunk bits (teams are aligned 16-lane groups).
#pragma unroll
    for (int m = 1; m < 16; m <<= 1) {
#pragma unroll
        for (int e = 0; e < NUM_EXPERTS; ++e)
            acc[e] += __shfl_xor(acc[e], m, 64);
    }

    if (c == 0) {
        float lf[NUM_EXPERTS];
#pragma unroll
        for (int e = 0; e < NUM_EXPERTS; ++e)
            lf[e] = (float)(acc[e] + (double)bias[e]);
        // first-occurrence argmax (matches jnp.argmax tie-break)
        float mx = lf[0];
        int idx = 0;
#pragma unroll
        for (int e = 1; e < NUM_EXPERTS; ++e)
            if (lf[e] > mx) { mx = lf[e]; idx = e; }
        float sum = 0.0f;
#pragma unroll
        for (int e = 0; e < NUM_EXPERTS; ++e)
            sum += expf(lf[e] - mx);
        float4* lp = (float4*)(out_logits + (size_t)tok * NUM_EXPERTS);
        lp[0] = make_float4(lf[0], lf[1], lf[2], lf[3]);
        lp[1] = make_float4(lf[4], lf[5], lf[6], lf[7]);
        out_pmax[tok] = 1.0f / sum;  // exp(mx-mx)/sum
        ws_idx[tok] = idx;
    }
}

// Kernel B: per-group inclusive cumsum of one-hot expert assignment + capacity
// mask. One block per group; thread tid owns tokens [tid*8, tid*8+8). Counts
// packed 16-bit x8 into 4 uint32 words; Hillis-Steele scan in LDS.
__global__ __launch_bounds__(256) void router_scan_kernel(
    const int* __restrict__ ws_idx, float* __restrict__ out_expert)
{
    __shared__ unsigned sb[4][256];
    const int g    = blockIdx.x;
    const int tid  = threadIdx.x;
    const int tok0 = g * NTOK + tid * 8;

    int idx[8];
#pragma unroll
    for (int j = 0; j < 8; ++j) idx[j] = ws_idx[tok0 + j];

    unsigned lc[4] = {0u, 0u, 0u, 0u};
#pragma unroll
    for (int j = 0; j < 8; ++j)
        lc[idx[j] >> 1] += 1u << ((idx[j] & 1) * 16);

#pragma unroll
    for (int w = 0; w < 4; ++w) sb[w][tid] = lc[w];
    __syncthreads();

    for (int off = 1; off < 256; off <<= 1) {
        unsigned v[4];
#pragma unroll
        for (int w = 0; w < 4; ++w)
            v[w] = (tid >= off) ? sb[w][tid - off] : 0u;
        __syncthreads();
#pragma unroll
        for (int w = 0; w < 4; ++w) sb[w][tid] += v[w];
        __syncthreads();
    }

    // exclusive prefix counts per expert (inclusive - local)
    unsigned run[NUM_EXPERTS];
#pragma unroll
    for (int e = 0; e < NUM_EXPERTS; ++e)
        run[e] = ((sb[e >> 1][tid] - lc[e >> 1]) >> ((e & 1) * 16)) & 0xFFFFu;

#pragma unroll
    for (int j = 0; j < 8; ++j) {
        const int e = idx[j];
        run[e] += 1u;  // inclusive token_priority for this token's expert
        const float keep = (run[e] <= CAPACITY) ? 1.0f : 0.0f;
        float vv[NUM_EXPERTS];
#pragma unroll
        for (int k = 0; k < NUM_EXPERTS; ++k)
            vv[k] = (k == e) ? keep : 0.0f;
        float4* op = (float4*)(out_expert + (size_t)(tok0 + j) * NUM_EXPERTS);
        op[0] = make_float4(vv[0], vv[1], vv[2], vv[3]);
        op[1] = make_float4(vv[4], vv[5], vv[6], vv[7]);
    }
}

extern "C" void kernel_launch(void* const* d_in, const int* in_sizes, int n_in,
                              void* d_out, int out_size, void* d_ws, size_t ws_size,
                              hipStream_t stream) {
    const float* hs = (const float*)d_in[0];
    const float* W  = (const float*)d_in[1];
    const float* b  = (const float*)d_in[2];

    float* out        = (float*)d_out;
    float* out_expert = out;                                      // [G,T,E] one-hot (as float)
    float* out_pmax   = out + (size_t)NTOKENS * NUM_EXPERTS;      // [G,T,1]
    float* out_logits = out_pmax + NTOKENS;                       // [G,T,E]
    int*   ws_idx     = (int*)d_ws;                               // [G*T] argmax expert ids

    router_logits_kernel<<<NTOKENS / 32, 512, 0, stream>>>(hs, W, b,
                                                           out_logits, out_pmax, ws_idx);
    router_scan_kernel<<<NGROUP, 256, 0, stream>>>(ws_idx, out_expert);
}

// Round 3
// 327.806 us; speedup vs baseline: 2.0280x; 2.0280x over previous
//
#include <hip/hip_runtime.h>
#include <math.h>

#define NUM_EXPERTS 8
#define CAPACITY 320
#define NGROUP 8
#define NTOK 2048
#define HID 2048
#define NTOKENS (NGROUP * NTOK)  // 16384

// Kernel A: router logits + softmax max + argmax.
// Block = 256 threads = 16 teams of 16 lanes; ONE token per team (grid 1024).
// No LDS: W (64 KB) is read through L1/L2 — hot after the first touch per CU.
// The hs stream is the only thing we need deep in the VMEM queue: each lane
// prefetches 8 float4 of hs (32 VGPRs) before any use, so every wave keeps
// ~8 HBM/L3 loads in flight. fp64 accumulation with the R1-verified per-lane
// order (c = lane&15, q = i*16+c, i ascending) -> bit-identical logits to the
// R1 kernel that passed at absmax 0.0039.
// __launch_bounds__(256,4): 128-VGPR cap — roomy (R2 lesson: a tight cap +
// fp64 acc arrays = scratch spills = 1 GB of garbage traffic).
__global__ __launch_bounds__(256, 4) void router_logits_kernel(
    const float* __restrict__ hs, const float* __restrict__ Wt,
    const float* __restrict__ bias,
    float* __restrict__ out_logits, float* __restrict__ out_pmax,
    int* __restrict__ ws_idx)
{
    const int tid  = threadIdx.x;
    const int c    = tid & 15;   // lane within team
    const int team = tid >> 4;   // 0..15
    const int tok  = blockIdx.x * 16 + team;

    const float4* hsv = (const float4*)(hs + (size_t)tok * HID);
    const float4* Wv  = (const float4*)Wt;

    double acc[NUM_EXPERTS];
#pragma unroll
    for (int e = 0; e < NUM_EXPERTS; ++e) acc[e] = 0.0;

#pragma unroll
    for (int ib = 0; ib < 4; ++ib) {
        // 8 hs chunks issued back-to-back: deep VMEM queue of useful bytes.
        float4 av[8];
#pragma unroll
        for (int j = 0; j < 8; ++j)
            av[j] = hsv[(ib * 8 + j) * 16 + c];

#pragma unroll
        for (int j = 0; j < 8; ++j) {
            const int q = (ib * 8 + j) * 16 + c;
            double ax = (double)av[j].x, ay = (double)av[j].y;
            double az = (double)av[j].z, aw = (double)av[j].w;
#pragma unroll
            for (int e = 0; e < NUM_EXPERTS; ++e) {
                float4 w = Wv[e * (HID / 4) + q];
                acc[e] += ax * (double)w.x + ay * (double)w.y +
                          az * (double)w.z + aw * (double)w.w;
            }
        }
    }

    // Butterfly over the 4 chunk bits (teams are aligned 16-lane groups).
#pragma unroll
    for (int m = 1; m < 16; m <<= 1) {
#pragma unroll
        for (int e = 0; e < NUM_EXPERTS; ++e)
            acc[e] += __shfl_xor(acc[e], m, 64);
    }

    if (c == 0) {
        float lf[NUM_EXPERTS];
#pragma unroll
        for (int e = 0; e < NUM_EXPERTS; ++e)
            lf[e] = (float)(acc[e] + (double)bias[e]);
        // first-occurrence argmax (matches jnp.argmax tie-break)
        float mx = lf[0];
        int idx = 0;
#pragma unroll
        for (int e = 1; e < NUM_EXPERTS; ++e)
            if (lf[e] > mx) { mx = lf[e]; idx = e; }
        float sum = 0.0f;
#pragma unroll
        for (int e = 0; e < NUM_EXPERTS; ++e)
            sum += expf(lf[e] - mx);
        float4* lp = (float4*)(out_logits + (size_t)tok * NUM_EXPERTS);
        lp[0] = make_float4(lf[0], lf[1], lf[2], lf[3]);
        lp[1] = make_float4(lf[4], lf[5], lf[6], lf[7]);
        out_pmax[tok] = 1.0f / sum;  // exp(mx-mx)/sum
        ws_idx[tok] = idx;
    }
}

// Kernel B: per-group inclusive cumsum of one-hot expert assignment + capacity
// mask. One block per group; thread tid owns tokens [tid*8, tid*8+8). Counts
// packed 16-bit x8 into 4 uint32 words; Hillis-Steele scan in LDS.
__global__ __launch_bounds__(256) void router_scan_kernel(
    const int* __restrict__ ws_idx, float* __restrict__ out_expert)
{
    __shared__ unsigned sb[4][256];
    const int g    = blockIdx.x;
    const int tid  = threadIdx.x;
    const int tok0 = g * NTOK + tid * 8;

    int idx[8];
#pragma unroll
    for (int j = 0; j < 8; ++j) idx[j] = ws_idx[tok0 + j];

    unsigned lc[4] = {0u, 0u, 0u, 0u};
#pragma unroll
    for (int j = 0; j < 8; ++j)
        lc[idx[j] >> 1] += 1u << ((idx[j] & 1) * 16);

#pragma unroll
    for (int w = 0; w < 4; ++w) sb[w][tid] = lc[w];
    __syncthreads();

    for (int off = 1; off < 256; off <<= 1) {
        unsigned v[4];
#pragma unroll
        for (int w = 0; w < 4; ++w)
            v[w] = (tid >= off) ? sb[w][tid - off] : 0u;
        __syncthreads();
#pragma unroll
        for (int w = 0; w < 4; ++w) sb[w][tid] += v[w];
        __syncthreads();
    }

    // exclusive prefix counts per expert (inclusive - local)
    unsigned run[NUM_EXPERTS];
#pragma unroll
    for (int e = 0; e < NUM_EXPERTS; ++e)
        run[e] = ((sb[e >> 1][tid] - lc[e >> 1]) >> ((e & 1) * 16)) & 0xFFFFu;

#pragma unroll
    for (int j = 0; j < 8; ++j) {
        const int e = idx[j];
        run[e] += 1u;  // inclusive token_priority for this token's expert
        const float keep = (run[e] <= CAPACITY) ? 1.0f : 0.0f;
        float vv[NUM_EXPERTS];
#pragma unroll
        for (int k = 0; k < NUM_EXPERTS; ++k)
            vv[k] = (k == e) ? keep : 0.0f;
        float4* op = (float4*)(out_expert + (size_t)(tok0 + j) * NUM_EXPERTS);
        op[0] = make_float4(vv[0], vv[1], vv[2], vv[3]);
        op[1] = make_float4(vv[4], vv[5], vv[6], vv[7]);
    }
}

extern "C" void kernel_launch(void* const* d_in, const int* in_sizes, int n_in,
                              void* d_out, int out_size, void* d_ws, size_t ws_size,
                              hipStream_t stream) {
    const float* hs = (const float*)d_in[0];
    const float* W  = (const float*)d_in[1];
    const float* b  = (const float*)d_in[2];

    float* out        = (float*)d_out;
    float* out_expert = out;                                      // [G,T,E] one-hot (as float)
    float* out_pmax   = out + (size_t)NTOKENS * NUM_EXPERTS;      // [G,T,1]
    float* out_logits = out_pmax + NTOKENS;                       // [G,T,E]
    int*   ws_idx     = (int*)d_ws;                               // [G*T] argmax expert ids

    router_logits_kernel<<<NTOKENS / 16, 256, 0, stream>>>(hs, W, b,
                                                           out_logits, out_pmax, ws_idx);
    router_scan_kernel<<<NGROUP, 256, 0, stream>>>(ws_idx, out_expert);
}

// Round 5
// 318.898 us; speedup vs baseline: 2.0847x; 1.0279x over previous
//
#include <hip/hip_runtime.h>
#include <math.h>

#define NUM_EXPERTS 8
#define CAPACITY 320
#define NGROUP 8
#define NTOK 2048
#define HID 2048
#define NTOKENS (NGROUP * NTOK)  // 16384

typedef float vfloat4 __attribute__((ext_vector_type(4)));  // native vector:
// __builtin_nontemporal_load requires scalar/native-vector, not HIP_vector_type.

// Kernel A: router logits + softmax max + argmax.
// Block = 256 threads = 16 teams of 16 lanes; ONE token per team (grid 1024
// -> 4096 waves = 16 waves/CU; R3 measured 47.7% occupancy, as designed).
//
// R3 lesson: batch-8 hs prefetch (32 VGPRs) + fp64 acc (16) overflowed the
// allocator's 64-VGPR occupancy target -> it SPILLED the accumulators every
// iteration (WRITE_SIZE 134 MB of scratch traffic, 195 us). R1's batch-4
// footprint ran at VGPR=48 with zero spill. So: batch 4, nothing deeper.
//
// hs loads are nontemporal (zero reuse; each 64B line is consumed whole by 4
// lanes of one instruction) so W — which at 64 KB overflows the 32 KB L1 —
// keeps as much L1 residency as possible. W otherwise streams from L2.
//
// fp64 accumulation, per-lane order identical to R1/R3 (q = i*16+c, i
// ascending) -> bit-identical logits, absmax 0.0039 verified twice.
__global__ __launch_bounds__(256, 4) void router_logits_kernel(
    const float* __restrict__ hs, const float* __restrict__ Wt,
    const float* __restrict__ bias,
    float* __restrict__ out_logits, float* __restrict__ out_pmax,
    int* __restrict__ ws_idx)
{
    const int tid  = threadIdx.x;
    const int c    = tid & 15;   // lane within team
    const int team = tid >> 4;   // 0..15
    const int tok  = blockIdx.x * 16 + team;

    const vfloat4* hsv = (const vfloat4*)(hs + (size_t)tok * HID);
    const vfloat4* Wv  = (const vfloat4*)Wt;

    double acc[NUM_EXPERTS];
#pragma unroll
    for (int e = 0; e < NUM_EXPERTS; ++e) acc[e] = 0.0;

#pragma unroll
    for (int ib = 0; ib < 8; ++ib) {
        // 4 hs chunks in flight before any use (R1-proven register footprint).
        vfloat4 av[4];
#pragma unroll
        for (int j = 0; j < 4; ++j)
            av[j] = __builtin_nontemporal_load(&hsv[(ib * 4 + j) * 16 + c]);

#pragma unroll
        for (int j = 0; j < 4; ++j) {
            const int q = (ib * 4 + j) * 16 + c;
            double ax = (double)av[j].x, ay = (double)av[j].y;
            double az = (double)av[j].z, aw = (double)av[j].w;
#pragma unroll
            for (int e = 0; e < NUM_EXPERTS; ++e) {
                vfloat4 w = Wv[e * (HID / 4) + q];
                acc[e] += ax * (double)w.x + ay * (double)w.y +
                          az * (double)w.z + aw * (double)w.w;
            }
        }
    }

    // Butterfly over the 4 chunk bits (teams are aligned 16-lane groups).
#pragma unroll
    for (int m = 1; m < 16; m <<= 1) {
#pragma unroll
        for (int e = 0; e < NUM_EXPERTS; ++e)
            acc[e] += __shfl_xor(acc[e], m, 64);
    }

    if (c == 0) {
        float lf[NUM_EXPERTS];
#pragma unroll
        for (int e = 0; e < NUM_EXPERTS; ++e)
            lf[e] = (float)(acc[e] + (double)bias[e]);
        // first-occurrence argmax (matches jnp.argmax tie-break)
        float mx = lf[0];
        int idx = 0;
#pragma unroll
        for (int e = 1; e < NUM_EXPERTS; ++e)
            if (lf[e] > mx) { mx = lf[e]; idx = e; }
        float sum = 0.0f;
#pragma unroll
        for (int e = 0; e < NUM_EXPERTS; ++e)
            sum += expf(lf[e] - mx);
        float4* lp = (float4*)(out_logits + (size_t)tok * NUM_EXPERTS);
        lp[0] = make_float4(lf[0], lf[1], lf[2], lf[3]);
        lp[1] = make_float4(lf[4], lf[5], lf[6], lf[7]);
        out_pmax[tok] = 1.0f / sum;  // exp(mx-mx)/sum
        ws_idx[tok] = idx;
    }
}

// Kernel B: per-group inclusive cumsum of one-hot expert assignment + capacity
// mask. One block per group; thread tid owns tokens [tid*8, tid*8+8). Counts
// packed 16-bit x8 into 4 uint32 words; Hillis-Steele scan in LDS.
__global__ __launch_bounds__(256) void router_scan_kernel(
    const int* __restrict__ ws_idx, float* __restrict__ out_expert)
{
    __shared__ unsigned sb[4][256];
    const int g    = blockIdx.x;
    const int tid  = threadIdx.x;
    const int tok0 = g * NTOK + tid * 8;

    int idx[8];
#pragma unroll
    for (int j = 0; j < 8; ++j) idx[j] = ws_idx[tok0 + j];

    unsigned lc[4] = {0u, 0u, 0u, 0u};
#pragma unroll
    for (int j = 0; j < 8; ++j)
        lc[idx[j] >> 1] += 1u << ((idx[j] & 1) * 16);

#pragma unroll
    for (int w = 0; w < 4; ++w) sb[w][tid] = lc[w];
    __syncthreads();

    for (int off = 1; off < 256; off <<= 1) {
        unsigned v[4];
#pragma unroll
        for (int w = 0; w < 4; ++w)
            v[w] = (tid >= off) ? sb[w][tid - off] : 0u;
        __syncthreads();
#pragma unroll
        for (int w = 0; w < 4; ++w) sb[w][tid] += v[w];
        __syncthreads();
    }

    // exclusive prefix counts per expert (inclusive - local)
    unsigned run[NUM_EXPERTS];
#pragma unroll
    for (int e = 0; e < NUM_EXPERTS; ++e)
        run[e] = ((sb[e >> 1][tid] - lc[e >> 1]) >> ((e & 1) * 16)) & 0xFFFFu;

#pragma unroll
    for (int j = 0; j < 8; ++j) {
        const int e = idx[j];
        run[e] += 1u;  // inclusive token_priority for this token's expert
        const float keep = (run[e] <= CAPACITY) ? 1.0f : 0.0f;
        float vv[NUM_EXPERTS];
#pragma unroll
        for (int k = 0; k < NUM_EXPERTS; ++k)
            vv[k] = (k == e) ? keep : 0.0f;
        float4* op = (float4*)(out_expert + (size_t)(tok0 + j) * NUM_EXPERTS);
        op[0] = make_float4(vv[0], vv[1], vv[2], vv[3]);
        op[1] = make_float4(vv[4], vv[5], vv[6], vv[7]);
    }
}

extern "C" void kernel_launch(void* const* d_in, const int* in_sizes, int n_in,
                              void* d_out, int out_size, void* d_ws, size_t ws_size,
                              hipStream_t stream) {
    const float* hs = (const float*)d_in[0];
    const float* W  = (const float*)d_in[1];
    const float* b  = (const float*)d_in[2];

    float* out        = (float*)d_out;
    float* out_expert = out;                                      // [G,T,E] one-hot (as float)
    float* out_pmax   = out + (size_t)NTOKENS * NUM_EXPERTS;      // [G,T,1]
    float* out_logits = out_pmax + NTOKENS;                       // [G,T,E]
    int*   ws_idx     = (int*)d_ws;                               // [G*T] argmax expert ids

    router_logits_kernel<<<NTOKENS / 16, 256, 0, stream>>>(hs, W, b,
                                                           out_logits, out_pmax, ws_idx);
    router_scan_kernel<<<NGROUP, 256, 0, stream>>>(ws_idx, out_expert);
}

// Round 6
// 244.158 us; speedup vs baseline: 2.7228x; 1.3061x over previous
//
#include <hip/hip_runtime.h>
#include <math.h>

#define NUM_EXPERTS 8
#define CAPACITY 320
#define NGROUP 8
#define NTOK 2048
#define HID 2048
#define NTOKENS (NGROUP * NTOK)  // 16384

typedef float vfloat4 __attribute__((ext_vector_type(4)));  // native vector:
// __builtin_nontemporal_load requires scalar/native-vector, not HIP_vector_type.

// Kernel A: router logits + softmax max + argmax.
// Block = 256 threads = 16 teams of 16 lanes; ONE token per team (grid 1024
// -> 16 waves/CU).
//
// R3/R5 lesson (proven by WRITE_SIZE == 128 dwords/thread in BOTH batch
// shapes): an explicit prefetch array `av[N]` gets SPILLED to scratch by the
// allocator, which prefers to hoist the unrolled W loads into registers.
// R1's idiom — load consumed inline in the same unrolled iteration, no named
// staging array — ran at VGPR=48 with zero spill. So: inline loads,
// #pragma unroll 4, and NO __launch_bounds__ (R5's bound made the allocator
// chase a 64-reg / 8-wave target by spilling; unconstrained, R1 chose 48).
//
// hs loads are nontemporal (zero reuse) so W — 64 KB, bigger than the 32 KB
// L1 — keeps L1/L2 residency.
//
// fp64 accumulation, per-lane order identical to R1/R3/R5 (q = i*16+c, i
// ascending) -> bit-identical logits, absmax 0.0039 verified three times.
__global__ void router_logits_kernel(
    const float* __restrict__ hs, const float* __restrict__ Wt,
    const float* __restrict__ bias,
    float* __restrict__ out_logits, float* __restrict__ out_pmax,
    int* __restrict__ ws_idx)
{
    const int tid  = threadIdx.x;
    const int c    = tid & 15;   // lane within team
    const int team = tid >> 4;   // 0..15
    const int tok  = blockIdx.x * 16 + team;

    const vfloat4* hsv = (const vfloat4*)(hs + (size_t)tok * HID);
    const vfloat4* Wv  = (const vfloat4*)Wt;

    double acc[NUM_EXPERTS];
#pragma unroll
    for (int e = 0; e < NUM_EXPERTS; ++e) acc[e] = 0.0;

#pragma unroll 4
    for (int i = 0; i < 32; ++i) {
        const int q = i * 16 + c;
        vfloat4 a = __builtin_nontemporal_load(&hsv[q]);
        double ax = (double)a.x, ay = (double)a.y;
        double az = (double)a.z, aw = (double)a.w;
#pragma unroll
        for (int e = 0; e < NUM_EXPERTS; ++e) {
            vfloat4 w = Wv[e * (HID / 4) + q];
            acc[e] += ax * (double)w.x + ay * (double)w.y +
                      az * (double)w.z + aw * (double)w.w;
        }
    }

    // Butterfly over the 4 chunk bits (teams are aligned 16-lane groups).
#pragma unroll
    for (int m = 1; m < 16; m <<= 1) {
#pragma unroll
        for (int e = 0; e < NUM_EXPERTS; ++e)
            acc[e] += __shfl_xor(acc[e], m, 64);
    }

    if (c == 0) {
        float lf[NUM_EXPERTS];
#pragma unroll
        for (int e = 0; e < NUM_EXPERTS; ++e)
            lf[e] = (float)(acc[e] + (double)bias[e]);
        // first-occurrence argmax (matches jnp.argmax tie-break)
        float mx = lf[0];
        int idx = 0;
#pragma unroll
        for (int e = 1; e < NUM_EXPERTS; ++e)
            if (lf[e] > mx) { mx = lf[e]; idx = e; }
        float sum = 0.0f;
#pragma unroll
        for (int e = 0; e < NUM_EXPERTS; ++e)
            sum += expf(lf[e] - mx);
        float4* lp = (float4*)(out_logits + (size_t)tok * NUM_EXPERTS);
        lp[0] = make_float4(lf[0], lf[1], lf[2], lf[3]);
        lp[1] = make_float4(lf[4], lf[5], lf[6], lf[7]);
        out_pmax[tok] = 1.0f / sum;  // exp(mx-mx)/sum
        ws_idx[tok] = idx;
    }
}

// Kernel B: per-group inclusive cumsum of one-hot expert assignment + capacity
// mask. One block per group; thread tid owns tokens [tid*8, tid*8+8). Counts
// packed 16-bit x8 into 4 uint32 words; Hillis-Steele scan in LDS.
__global__ __launch_bounds__(256) void router_scan_kernel(
    const int* __restrict__ ws_idx, float* __restrict__ out_expert)
{
    __shared__ unsigned sb[4][256];
    const int g    = blockIdx.x;
    const int tid  = threadIdx.x;
    const int tok0 = g * NTOK + tid * 8;

    int idx[8];
#pragma unroll
    for (int j = 0; j < 8; ++j) idx[j] = ws_idx[tok0 + j];

    unsigned lc[4] = {0u, 0u, 0u, 0u};
#pragma unroll
    for (int j = 0; j < 8; ++j)
        lc[idx[j] >> 1] += 1u << ((idx[j] & 1) * 16);

#pragma unroll
    for (int w = 0; w < 4; ++w) sb[w][tid] = lc[w];
    __syncthreads();

    for (int off = 1; off < 256; off <<= 1) {
        unsigned v[4];
#pragma unroll
        for (int w = 0; w < 4; ++w)
            v[w] = (tid >= off) ? sb[w][tid - off] : 0u;
        __syncthreads();
#pragma unroll
        for (int w = 0; w < 4; ++w) sb[w][tid] += v[w];
        __syncthreads();
    }

    // exclusive prefix counts per expert (inclusive - local)
    unsigned run[NUM_EXPERTS];
#pragma unroll
    for (int e = 0; e < NUM_EXPERTS; ++e)
        run[e] = ((sb[e >> 1][tid] - lc[e >> 1]) >> ((e & 1) * 16)) & 0xFFFFu;

#pragma unroll
    for (int j = 0; j < 8; ++j) {
        const int e = idx[j];
        run[e] += 1u;  // inclusive token_priority for this token's expert
        const float keep = (run[e] <= CAPACITY) ? 1.0f : 0.0f;
        float vv[NUM_EXPERTS];
#pragma unroll
        for (int k = 0; k < NUM_EXPERTS; ++k)
            vv[k] = (k == e) ? keep : 0.0f;
        float4* op = (float4*)(out_expert + (size_t)(tok0 + j) * NUM_EXPERTS);
        op[0] = make_float4(vv[0], vv[1], vv[2], vv[3]);
        op[1] = make_float4(vv[4], vv[5], vv[6], vv[7]);
    }
}

extern "C" void kernel_launch(void* const* d_in, const int* in_sizes, int n_in,
                              void* d_out, int out_size, void* d_ws, size_t ws_size,
                              hipStream_t stream) {
    const float* hs = (const float*)d_in[0];
    const float* W  = (const float*)d_in[1];
    const float* b  = (const float*)d_in[2];

    float* out        = (float*)d_out;
    float* out_expert = out;                                      // [G,T,E] one-hot (as float)
    float* out_pmax   = out + (size_t)NTOKENS * NUM_EXPERTS;      // [G,T,1]
    float* out_logits = out_pmax + NTOKENS;                       // [G,T,E]
    int*   ws_idx     = (int*)d_ws;                               // [G*T] argmax expert ids

    router_logits_kernel<<<NTOKENS / 16, 256, 0, stream>>>(hs, W, b,
                                                           out_logits, out_pmax, ws_idx);
    router_scan_kernel<<<NGROUP, 256, 0, stream>>>(ws_idx, out_expert);
}

// Round 7
// 220.539 us; speedup vs baseline: 3.0145x; 1.1071x over previous
//
#include <hip/hip_runtime.h>
#include <math.h>

#define NUM_EXPERTS 8
#define CAPACITY 320
#define NGROUP 8
#define NTOK 2048
#define HID 2048
#define NTOKENS (NGROUP * NTOK)  // 16384

typedef float vfloat4 __attribute__((ext_vector_type(4)));  // native vector:
// __builtin_nontemporal_load requires scalar/native-vector, not HIP_vector_type.

// Kernel A: router logits + softmax max + argmax.
// Block = 256 threads = 8 teams of 32 lanes; TWO tokens per team
// (16 tokens/block, grid 1024 -> 16 waves/CU, same as R6).
//
// Why 2 tokens x 32 lanes (vs R6's 1 token x 16 lanes): R6 ran latency-bound
// at VGPR=32 — ~4 loads in flight/lane, only 1-in-9 being hs (the other 8 are
// W reloads) -> ~2 TB/s hs ceiling, 87 us. Here each iteration issues 2 hs +
// 8 W loads (hs fraction 2.3x higher per queue slot) and every W load feeds
// two tokens' FMAs, halving W cache traffic to 536 MB.
//
// R3/R5/R6 spill lesson: NO staging arrays, NO __launch_bounds__ — inline
// load->consume only. (Explicit av[] prefetch arrays get demoted to scratch:
// WRITE_SIZE showed exactly 128 spilled dwords/thread in both batch shapes.)
//
// hs loads are nontemporal (zero reuse) so W — 64 KB, bigger than the 32 KB
// L1 — keeps L1/L2 residency.
//
// fp64 accumulation. Per-lane order differs from R1/R6 (32-lane partition:
// q = i*32+c) but fp64 assoc error ~1e-13 is invisible at the 8.4e-2
// threshold and cannot flip argmax decisions vs the ~exact value.
__global__ void router_logits_kernel(
    const float* __restrict__ hs, const float* __restrict__ Wt,
    const float* __restrict__ bias,
    float* __restrict__ out_logits, float* __restrict__ out_pmax,
    int* __restrict__ ws_idx)
{
    const int tid  = threadIdx.x;
    const int c    = tid & 31;   // lane within 32-lane team
    const int team = tid >> 5;   // 0..7
    const int tokA = blockIdx.x * 16 + team * 2;
    const int tokB = tokA + 1;

    const vfloat4* hsA = (const vfloat4*)(hs + (size_t)tokA * HID);
    const vfloat4* hsB = (const vfloat4*)(hs + (size_t)tokB * HID);
    const vfloat4* Wv  = (const vfloat4*)Wt;

    double accA[NUM_EXPERTS], accB[NUM_EXPERTS];
#pragma unroll
    for (int e = 0; e < NUM_EXPERTS; ++e) { accA[e] = 0.0; accB[e] = 0.0; }

#pragma unroll 4
    for (int i = 0; i < 16; ++i) {
        const int q = i * 32 + c;   // float4 index within a row (H/4 = 512)
        vfloat4 a = __builtin_nontemporal_load(&hsA[q]);
        vfloat4 b = __builtin_nontemporal_load(&hsB[q]);
        double ax = (double)a.x, ay = (double)a.y;
        double az = (double)a.z, aw = (double)a.w;
        double bx = (double)b.x, by = (double)b.y;
        double bz = (double)b.z, bw = (double)b.w;
#pragma unroll
        for (int e = 0; e < NUM_EXPERTS; ++e) {
            vfloat4 w = Wv[e * (HID / 4) + q];
            double wx = (double)w.x, wy = (double)w.y;
            double wz = (double)w.z, ww = (double)w.w;
            accA[e] += ax * wx + ay * wy + az * wz + aw * ww;
            accB[e] += bx * wx + by * wy + bz * wz + bw * ww;
        }
    }

    // Butterfly over the 5 chunk bits (teams are aligned 32-lane groups).
#pragma unroll
    for (int m = 1; m < 32; m <<= 1) {
#pragma unroll
        for (int e = 0; e < NUM_EXPERTS; ++e) {
            accA[e] += __shfl_xor(accA[e], m, 64);
            accB[e] += __shfl_xor(accB[e], m, 64);
        }
    }

    if (c == 0) {
        auto emit = [&](const double* acc, int t) {
            float lf[NUM_EXPERTS];
#pragma unroll
            for (int e = 0; e < NUM_EXPERTS; ++e)
                lf[e] = (float)(acc[e] + (double)bias[e]);
            // first-occurrence argmax (matches jnp.argmax tie-break)
            float mx = lf[0];
            int idx = 0;
#pragma unroll
            for (int e = 1; e < NUM_EXPERTS; ++e)
                if (lf[e] > mx) { mx = lf[e]; idx = e; }
            float sum = 0.0f;
#pragma unroll
            for (int e = 0; e < NUM_EXPERTS; ++e)
                sum += expf(lf[e] - mx);
            float4* lp = (float4*)(out_logits + (size_t)t * NUM_EXPERTS);
            lp[0] = make_float4(lf[0], lf[1], lf[2], lf[3]);
            lp[1] = make_float4(lf[4], lf[5], lf[6], lf[7]);
            out_pmax[t] = 1.0f / sum;   // exp(mx-mx)/sum
            ws_idx[t] = idx;
        };
        emit(accA, tokA);
        emit(accB, tokB);
    }
}

// Kernel B: per-group inclusive cumsum of one-hot expert assignment + capacity
// mask. One block per group; thread tid owns tokens [tid*8, tid*8+8). Counts
// packed 16-bit x8 into 4 uint32 words; Hillis-Steele scan in LDS.
__global__ __launch_bounds__(256) void router_scan_kernel(
    const int* __restrict__ ws_idx, float* __restrict__ out_expert)
{
    __shared__ unsigned sb[4][256];
    const int g    = blockIdx.x;
    const int tid  = threadIdx.x;
    const int tok0 = g * NTOK + tid * 8;

    int idx[8];
#pragma unroll
    for (int j = 0; j < 8; ++j) idx[j] = ws_idx[tok0 + j];

    unsigned lc[4] = {0u, 0u, 0u, 0u};
#pragma unroll
    for (int j = 0; j < 8; ++j)
        lc[idx[j] >> 1] += 1u << ((idx[j] & 1) * 16);

#pragma unroll
    for (int w = 0; w < 4; ++w) sb[w][tid] = lc[w];
    __syncthreads();

    for (int off = 1; off < 256; off <<= 1) {
        unsigned v[4];
#pragma unroll
        for (int w = 0; w < 4; ++w)
            v[w] = (tid >= off) ? sb[w][tid - off] : 0u;
        __syncthreads();
#pragma unroll
        for (int w = 0; w < 4; ++w) sb[w][tid] += v[w];
        __syncthreads();
    }

    // exclusive prefix counts per expert (inclusive - local)
    unsigned run[NUM_EXPERTS];
#pragma unroll
    for (int e = 0; e < NUM_EXPERTS; ++e)
        run[e] = ((sb[e >> 1][tid] - lc[e >> 1]) >> ((e & 1) * 16)) & 0xFFFFu;

#pragma unroll
    for (int j = 0; j < 8; ++j) {
        const int e = idx[j];
        run[e] += 1u;  // inclusive token_priority for this token's expert
        const float keep = (run[e] <= CAPACITY) ? 1.0f : 0.0f;
        float vv[NUM_EXPERTS];
#pragma unroll
        for (int k = 0; k < NUM_EXPERTS; ++k)
            vv[k] = (k == e) ? keep : 0.0f;
        float4* op = (float4*)(out_expert + (size_t)(tok0 + j) * NUM_EXPERTS);
        op[0] = make_float4(vv[0], vv[1], vv[2], vv[3]);
        op[1] = make_float4(vv[4], vv[5], vv[6], vv[7]);
    }
}

extern "C" void kernel_launch(void* const* d_in, const int* in_sizes, int n_in,
                              void* d_out, int out_size, void* d_ws, size_t ws_size,
                              hipStream_t stream) {
    const float* hs = (const float*)d_in[0];
    const float* W  = (const float*)d_in[1];
    const float* b  = (const float*)d_in[2];

    float* out        = (float*)d_out;
    float* out_expert = out;                                      // [G,T,E] one-hot (as float)
    float* out_pmax   = out + (size_t)NTOKENS * NUM_EXPERTS;      // [G,T,1]
    float* out_logits = out_pmax + NTOKENS;                       // [G,T,E]
    int*   ws_idx     = (int*)d_ws;                               // [G*T] argmax expert ids

    router_logits_kernel<<<NTOKENS / 16, 256, 0, stream>>>(hs, W, b,
                                                           out_logits, out_pmax, ws_idx);
    router_scan_kernel<<<NGROUP, 256, 0, stream>>>(ws_idx, out_expert);
}